// Round 20
// baseline (232.538 us; speedup 1.0000x reference)
//
#include <hip/hip_runtime.h>
#include <hip/hip_bf16.h>
#include <cstddef>

// Problem constants: N=128, L=200, LE=201, E=128, A=16 aspects, NB=2, H=2, HD=64, TEMP=0.2
typedef __attribute__((ext_vector_type(8))) short bf16x8;
typedef __attribute__((ext_vector_type(4))) float f32x4;
typedef unsigned short ushort_t;

__device__ __forceinline__ short f2bf(float f) {
    __hip_bfloat16 h = __float2bfloat16(f);
    return __builtin_bit_cast(short, h);
}
__device__ __forceinline__ float bf2f(short s) {
    unsigned u = ((unsigned)(unsigned short)s) << 16;
    return __builtin_bit_cast(float, u);
}
__device__ __forceinline__ unsigned pk2(float a, float b) {
    return (unsigned)(unsigned short)f2bf(a) | ((unsigned)(unsigned short)f2bf(b) << 16);
}

// ---------------------------------------------------------------------------
// Convert + permute ALL weight matrices to fragment-major layout.
// Aspect matrices (mat<16) get the residual identity folded in: W' = W + I.
__global__ void cvt_all(const float* __restrict__ s0, const float* __restrict__ s1,
                        const float* __restrict__ s2, const float* __restrict__ s3,
                        const float* __restrict__ s4, ushort_t* __restrict__ dst) {
    const int i = blockIdx.x * 256 + threadIdx.x;   // < 458752
    const int mat = i >> 14;          // 28 matrices of 16384
    const int wm = i & 16383;
    const int blk = wm >> 9;          // t*4 + f
    const int t = blk >> 2, f = blk & 3;
    const int lane = (wm >> 3) & 63;
    const int j = wm & 7;
    const int g4 = lane >> 4, nn = lane & 15;
    const int o = t * 16 + nn;
    const int k = f * 32 + g4 * 8 + j;
    const int srcoff = o * 128 + k;
    const float* src; int mbase;
    if (mat < 16)      { src = s0; mbase = mat; }
    else if (mat < 22) { src = s1; mbase = mat - 16; }
    else if (mat < 24) { src = s2; mbase = mat - 22; }
    else if (mat < 26) { src = s3; mbase = mat - 24; }
    else               { src = s4; mbase = mat - 26; }
    float v = src[(size_t)mbase * 16384 + srcoff];
    if (mat < 16 && o == k) v += 1.f;
    dst[i] = (ushort_t)f2bf(v);
}

// ---------------------------------------------------------------------------
// Fused aspects kernel v8: 16 rows/block (2 blocks/CU for latency hiding),
// 512 threads. Gather fused; residual folded into W'; norms + gate logits
// via MFMA (gram reused for mi); seqs written for kv rows.
__global__ __launch_bounds__(512, 2) void aspects2_kernel(
        const float* __restrict__ item_emb,
        const int* __restrict__ log_seqs, const int* __restrict__ pos_seqs,
        const int* __restrict__ neg_seqs,
        const ushort_t* __restrict__ Wab,
        const float* __restrict__ w_weight,
        const float* __restrict__ pos_emb,
        float* __restrict__ Gout, float* __restrict__ seqs,
        float* __restrict__ validE, float* __restrict__ validL,
        float* __restrict__ pInd, float* __restrict__ pCent,
        int nLossBlocks) {
    __shared__ ushort_t rsb[16 * 2184];    // v = x@W'^T, bf16 (68.3 KB)
    __shared__ ushort_t xsb[16 * 136];     // x bf16 (4.3 KB)
    __shared__ ushort_t wal_b[128];        // w_a bf16
    __shared__ int sidx[16];
    __shared__ float s_red[256];           // nrm2 -> sg   (row*16 + a)
    __shared__ float s_lg[256];            // raw logit -> gateW
    __shared__ float s_pos[256];           // pos_s*5
    __shared__ float vld[16];
    __shared__ float centw[16];
    __shared__ float miw[16];

    const int tid = threadIdx.x;
    const int row0 = blockIdx.x * 16;
    const bool losses = (int)blockIdx.x < nLossBlocks;
    const int lane = tid & 63, w = tid >> 6;       // w in 0..7
    const int g4 = lane >> 4, nn = lane & 15;

    // ---- fused gather: indices + valid flags ----
    if (tid < 16) {
        const int rg = row0 + tid;
        int si; float vl;
        if (rg < 25728) {                   // kv region (N x 201)
            const int nq = rg / 201, l = rg % 201;
            if (l < 200) { si = log_seqs[nq * 200 + l]; vl = (si != 0) ? 1.f : 0.f; }
            else { vl = (log_seqs[nq * 200 + 199] != 0) ? 1.f : 0.f; si = pos_seqs[nq * 200 + 199]; }
            validE[rg] = vl;
        } else {                            // neg region (N x 200)
            const int rr = rg - 25728;
            vl = (log_seqs[rr] != 0) ? 1.f : 0.f;
            si = neg_seqs[rr];
            validL[rr] = vl;
        }
        sidx[tid] = si;
        vld[tid] = vl;
    }
    if (tid < 128) wal_b[tid] = (ushort_t)f2bf(w_weight[128 + tid]);
    __syncthreads();

    // ---- stage x: 256 threads (16 rows x 16 thr x 8 floats) ----
    if (tid < 256) {
        const int r = tid >> 4, c8 = (tid & 15) * 8;
        const float vl = vld[r];
        const float* px = &item_emb[(size_t)sidx[r] * 128 + c8];
        const float4 a = *(const float4*)px;
        const float4 b = *(const float4*)(px + 4);
        *(int2*)&xsb[r * 136 + c8] = make_int2(
            (int)pk2(a.x * vl, a.y * vl), (int)pk2(a.z * vl, a.w * vl));
        *(int2*)&xsb[r * 136 + c8 + 4] = make_int2(
            (int)pk2(b.x * vl, b.y * vl), (int)pk2(b.z * vl, b.w * vl));
    }
    __syncthreads();

    bf16x8 xf[4], waf[4];
#pragma unroll
    for (int f = 0; f < 4; ++f) {
        xf[f] = *(const bf16x8*)&xsb[nn * 136 + f * 32 + g4 * 8];
        waf[f] = *(const bf16x8*)&wal_b[f * 32 + g4 * 8];   // broadcast (nn-invariant)
    }

    // ---- GEMM phase: wave w -> aspects 2w, 2w+1 ----
    for (int al = 0; al < 2; ++al) {
        const int a = w * 2 + al;
        const ushort_t* wbase = Wab + (size_t)a * 16384 + lane * 8;
#pragma unroll
        for (int t = 0; t < 8; ++t) {
            f32x4 d0 = {0.f, 0.f, 0.f, 0.f};
#pragma unroll
            for (int f = 0; f < 4; ++f) {
                bf16x8 wf = *(const bf16x8*)&wbase[(t * 4 + f) * 512];
                d0 = __builtin_amdgcn_mfma_f32_16x16x32_bf16(wf, xf[f], d0, 0, 0, 0);
            }
            const int o0 = t * 16 + g4 * 4;
            *(int2*)&rsb[nn * 2184 + a * 136 + o0] = make_int2(
                (int)pk2(d0[0], d0[1]), (int)pk2(d0[2], d0[3]));
        }
    }
    __syncthreads();

    // ---- norm/logit phase: wave w -> rows 2w, 2w+1 via MFMA ----
    f32x4 gram0 = {0.f,0.f,0.f,0.f}, gram1 = gram0;
#pragma unroll
    for (int rl = 0; rl < 2; ++rl) {
        const int row = w * 2 + rl;
        f32x4 dgr = {0.f, 0.f, 0.f, 0.f}, dlp = dgr;
#pragma unroll
        for (int f = 0; f < 4; ++f) {
            bf16x8 fr = *(const bf16x8*)&rsb[row * 2184 + nn * 136 + f * 32 + g4 * 8];
            dgr = __builtin_amdgcn_mfma_f32_16x16x32_bf16(fr, fr, dgr, 0, 0, 0);
            dlp = __builtin_amdgcn_mfma_f32_16x16x32_bf16(fr, waf[f], dlp, 0, 0, 0);
        }
        if (rl == 0) gram0 = dgr; else gram1 = dgr;
        if (g4 == (nn >> 2)) s_red[row * 16 + nn] = dgr[nn & 3];   // diagonal = nrm^2
        if (nn == 0) {
#pragma unroll
            for (int r = 0; r < 4; ++r) s_lg[row * 16 + g4 * 4 + r] = dlp[r];
        }
    }
    __syncthreads();

    // ---- per-(row,aspect) scalars + gate softmax (tid = row*16 + a) ----
    if (tid < 256) {
        const float nrm = sqrtf(s_red[tid]);
        const float inv1 = 1.f / (nrm + 1e-8f);
        const float n2 = nrm * inv1;
        const float sg = inv1 / (n2 + 1e-8f);
        const float ts = n2 / (n2 + 1e-8f);
        const float logit = s_lg[tid] * inv1;
        float mx = logit;
#pragma unroll
        for (int m = 1; m < 16; m <<= 1) mx = fmaxf(mx, __shfl_xor(mx, m, 16));
        const float e = __expf(logit - mx);
        float ssum = e;
#pragma unroll
        for (int m = 1; m < 16; m <<= 1) ssum += __shfl_xor(ssum, m, 16);
        s_red[tid] = sg;
        s_pos[tid] = ts * ts * 5.f;
        s_lg[tid] = (e / ssum + 0.0625f) * inv1;
    }
    __syncthreads();

    // ---- G phase (+ fused seqs write): thread -> (row = tid>>5, o4) ----
    {
        const int row = tid >> 5, ol = tid & 31, o4 = ol * 4;
        float g[4] = {0.f, 0.f, 0.f, 0.f};
        float sr[4] = {0.f, 0.f, 0.f, 0.f};
#pragma unroll
        for (int a = 0; a < 16; ++a) {
            const int2 pk = *(const int2*)&rsb[row * 2184 + a * 136 + o4];
            const float v0 = __builtin_bit_cast(float, ((unsigned)pk.x) << 16);
            const float v1 = __builtin_bit_cast(float, ((unsigned)pk.x) & 0xFFFF0000u);
            const float v2 = __builtin_bit_cast(float, ((unsigned)pk.y) << 16);
            const float v3 = __builtin_bit_cast(float, ((unsigned)pk.y) & 0xFFFF0000u);
            const float gw = s_lg[row * 16 + a];
            g[0] += v0 * gw; g[1] += v1 * gw; g[2] += v2 * gw; g[3] += v3 * gw;
            if (losses) { sr[0] += v0; sr[1] += v1; sr[2] += v2; sr[3] += v3; }
        }
        *(float4*)&Gout[(size_t)(row0 + row) * 128 + o4] = make_float4(g[0], g[1], g[2], g[3]);
        if (losses) {
            const int rg = row0 + row;
            const int nq = rg / 201, l = rg % 201;
            if (l < 200) {
                const float4 p0 = *(const float4*)&pos_emb[l * 128 + o4];
                const float vv = vld[row];
                float* so = &seqs[(size_t)(nq * 200 + l) * 128 + o4];
                const float SQ = 11.313708498984761f;
                *(float4*)so = make_float4((g[0] * SQ + p0.x) * vv, (g[1] * SQ + p0.y) * vv,
                                           (g[2] * SQ + p0.z) * vv, (g[3] * SQ + p0.w) * vv);
            }
            const int2 xk = *(const int2*)&xsb[row * 136 + o4];
            const float x0 = __builtin_bit_cast(float, ((unsigned)xk.x) << 16);
            const float x1 = __builtin_bit_cast(float, ((unsigned)xk.x) & 0xFFFF0000u);
            const float x2 = __builtin_bit_cast(float, ((unsigned)xk.y) << 16);
            const float x3 = __builtin_bit_cast(float, ((unsigned)xk.y) & 0xFFFF0000u);
            const float d0 = 2.f * x0 - sr[0] * 0.0625f;
            const float d1 = 2.f * x1 - sr[1] * 0.0625f;
            const float d2 = 2.f * x2 - sr[2] * 0.0625f;
            const float d3 = 2.f * x3 - sr[3] * 0.0625f;
            float c = d0 * d0 + d1 * d1 + d2 * d2 + d3 * d3;
#pragma unroll
            for (int m = 1; m < 32; m <<= 1) c += __shfl_xor(c, m, 64);
            if (ol == 0) centw[row] = sqrtf(c) * vld[row];
        }
    }

    // ---- mi loss: reuse gram registers (rows 2w, 2w+1) ----
    if (losses) {
#pragma unroll
        for (int rl = 0; rl < 2; ++rl) {
            const int row = w * 2 + rl;
            const f32x4 dd = (rl == 0) ? gram0 : gram1;
            const float sgb = s_red[row * 16 + nn];
            float mis = 0.f;
#pragma unroll
            for (int r = 0; r < 4; ++r) {
                const int a = g4 * 4 + r;
                const float sga = s_red[row * 16 + a];
                float eb = __expf(5.f * dd[r] * sga * sgb);
#pragma unroll
                for (int m = 1; m < 16; m <<= 1) eb += __shfl_xor(eb, m, 16);
                mis += -(s_pos[row * 16 + a] - logf(eb));
            }
            mis += __shfl_xor(mis, 16, 64);
            mis += __shfl_xor(mis, 32, 64);
            if (lane == 0) miw[row] = mis * vld[row];
        }
        __syncthreads();
        if (tid == 0) {
            float si = 0.f, sc = 0.f;
#pragma unroll
            for (int r = 0; r < 16; ++r) { si += miw[r]; sc += centw[r]; }
            pInd[blockIdx.x] = si;
            pCent[blockIdx.x] = sc;
        }
    }
}

// ---------------------------------------------------------------------------
// Fused QKV projection: ONE WAVE per 16-row tile (grid 1600) for machine fill.
__global__ __launch_bounds__(64) void qkv_kernel(const float* __restrict__ X,
                                                 const ushort_t* __restrict__ W3,
                                                 const float* __restrict__ b3,
                                                 const float* __restrict__ lng,
                                                 const float* __restrict__ lnb,
                                                 float* __restrict__ Xn,
                                                 ushort_t* __restrict__ qo,
                                                 ushort_t* __restrict__ ko,
                                                 ushort_t* __restrict__ vo) {
    const int lane = threadIdx.x & 63;
    const int q = lane >> 4, nn = lane & 15;
    const int m0 = blockIdx.x * 16;
    float xv[4][8];
    float s = 0.f, sq = 0.f;
    const float* xr = &X[(size_t)(m0 + nn) * 128];
#pragma unroll
    for (int f = 0; f < 4; ++f) {
        const float4 a = *(const float4*)&xr[f * 32 + q * 8];
        const float4 b = *(const float4*)&xr[f * 32 + q * 8 + 4];
        xv[f][0] = a.x; xv[f][1] = a.y; xv[f][2] = a.z; xv[f][3] = a.w;
        xv[f][4] = b.x; xv[f][5] = b.y; xv[f][6] = b.z; xv[f][7] = b.w;
        s += (a.x + a.y) + (a.z + a.w) + (b.x + b.y) + (b.z + b.w);
        sq += (a.x * a.x + a.y * a.y) + (a.z * a.z + a.w * a.w)
            + (b.x * b.x + b.y * b.y) + (b.z * b.z + b.w * b.w);
    }
    bf16x8 afr[4];   // raw (K/V operand)
#pragma unroll
    for (int f = 0; f < 4; ++f) {
        bf16x8 v;
#pragma unroll
        for (int j = 0; j < 8; ++j) v[j] = f2bf(xv[f][j]);
        afr[f] = v;
    }
    s += __shfl_xor(s, 16, 64);  s += __shfl_xor(s, 32, 64);
    sq += __shfl_xor(sq, 16, 64); sq += __shfl_xor(sq, 32, 64);
    const float mean = s * 0.0078125f;
    const float var = fmaxf(sq * 0.0078125f - mean * mean, 0.f);
    const float inv = rsqrtf(var + 1e-8f);
    bf16x8 afq[4];   // normalized (Q operand)
#pragma unroll
    for (int f = 0; f < 4; ++f) {
        const int c0 = f * 32 + q * 8;
        const float4 ga = *(const float4*)&lng[c0];
        const float4 gb = *(const float4*)&lng[c0 + 4];
        const float4 ba = *(const float4*)&lnb[c0];
        const float4 bb = *(const float4*)&lnb[c0 + 4];
        float y[8];
        y[0] = (xv[f][0] - mean) * inv * ga.x + ba.x;
        y[1] = (xv[f][1] - mean) * inv * ga.y + ba.y;
        y[2] = (xv[f][2] - mean) * inv * ga.z + ba.z;
        y[3] = (xv[f][3] - mean) * inv * ga.w + ba.w;
        y[4] = (xv[f][4] - mean) * inv * gb.x + bb.x;
        y[5] = (xv[f][5] - mean) * inv * gb.y + bb.y;
        y[6] = (xv[f][6] - mean) * inv * gb.z + bb.z;
        y[7] = (xv[f][7] - mean) * inv * gb.w + bb.w;
        float* xo = &Xn[(size_t)(m0 + nn) * 128 + c0];
        *(float4*)xo       = make_float4(y[0], y[1], y[2], y[3]);
        *(float4*)(xo + 4) = make_float4(y[4], y[5], y[6], y[7]);
        bf16x8 v;
#pragma unroll
        for (int j = 0; j < 8; ++j) v[j] = f2bf(y[j]);
        afq[f] = v;
    }
    ushort_t* const outs[3] = {qo, ko, vo};
#pragma unroll
    for (int mi = 0; mi < 3; ++mi) {
        const ushort_t* wbase = W3 + (size_t)mi * 16384 + lane * 8;
        f32x4 acc[8];
#pragma unroll
        for (int t = 0; t < 8; ++t) acc[t] = (f32x4){0.f, 0.f, 0.f, 0.f};
#pragma unroll
        for (int t = 0; t < 8; ++t) {
#pragma unroll
            for (int f = 0; f < 4; ++f) {
                bf16x8 b = *(const bf16x8*)&wbase[(t * 4 + f) * 512];
                acc[t] = __builtin_amdgcn_mfma_f32_16x16x32_bf16(
                    (mi == 0) ? afq[f] : afr[f], b, acc[t], 0, 0, 0);
            }
        }
        const float* bi = b3 + mi * 128;
        ushort_t* outp = outs[mi];
#pragma unroll
        for (int t = 0; t < 8; ++t) {
            const int n = t * 16 + nn;
            const float bv = bi[n];
#pragma unroll
            for (int r = 0; r < 4; ++r) {
                const int row = m0 + q * 4 + r;
                outp[(size_t)row * 128 + n] = (ushort_t)f2bf(acc[t][r] + bv);
            }
        }
    }
}

// ---------------------------------------------------------------------------
// Fused FFN block, ONE WAVE per 16-row tile (grid 1600).
// LAST=1: final LN + pos/neg logit dots fused (no seqs write).
template <int LAST>
__global__ __launch_bounds__(64) void ffn_kernel(const ushort_t* __restrict__ attno,
                                                 const ushort_t* __restrict__ outWb,
                                                 const float* __restrict__ outB,
                                                 const float* __restrict__ resQn,
                                                 const float* __restrict__ lng,
                                                 const float* __restrict__ lnb,
                                                 const ushort_t* __restrict__ c1wb,
                                                 const float* __restrict__ c1b,
                                                 const ushort_t* __restrict__ c2wb,
                                                 const float* __restrict__ c2b,
                                                 const float* __restrict__ validL,
                                                 float* __restrict__ seqs,
                                                 const float* __restrict__ lastg,
                                                 const float* __restrict__ lastb,
                                                 const float* __restrict__ G,
                                                 const float* __restrict__ negt,
                                                 float* __restrict__ outp) {
    __shared__ ushort_t hls[16 * 136];   // 4.4 KB, holds y then h (bf16)
    const int lane = threadIdx.x & 63;
    const int q = lane >> 4, nn = lane & 15;
    const int m0 = blockIdx.x * 16;

    bf16x8 af[4];
    {
        const ushort_t* xb = &attno[(size_t)(m0 + nn) * 128];
#pragma unroll
        for (int f = 0; f < 4; ++f) af[f] = *(const bf16x8*)&xb[f * 32 + q * 8];
    }
    f32x4 acc[8];
#pragma unroll
    for (int t = 0; t < 8; ++t) acc[t] = (f32x4){0.f, 0.f, 0.f, 0.f};
    {
        const ushort_t* wbase = outWb + lane * 8;
#pragma unroll
        for (int t = 0; t < 8; ++t)
#pragma unroll
            for (int f = 0; f < 4; ++f) {
                bf16x8 b = *(const bf16x8*)&wbase[(t * 4 + f) * 512];
                acc[t] = __builtin_amdgcn_mfma_f32_16x16x32_bf16(af[f], b, acc[t], 0, 0, 0);
            }
    }
    float y[8][4];
    float s[4] = {0.f, 0.f, 0.f, 0.f}, sq[4] = {0.f, 0.f, 0.f, 0.f};
#pragma unroll
    for (int t = 0; t < 8; ++t) {
        const int n = t * 16 + nn;
        const float bi = outB[n];
#pragma unroll
        for (int r = 0; r < 4; ++r) {
            const float v = acc[t][r] + bi + resQn[(size_t)(m0 + q * 4 + r) * 128 + n];
            y[t][r] = v;
            s[r] += v;
            sq[r] += v * v;
        }
    }
#pragma unroll
    for (int m = 1; m < 16; m <<= 1) {
#pragma unroll
        for (int r = 0; r < 4; ++r) {
            s[r] += __shfl_xor(s[r], m, 64);
            sq[r] += __shfl_xor(sq[r], m, 64);
        }
    }
#pragma unroll
    for (int r = 0; r < 4; ++r) {
        const float mean = s[r] * 0.0078125f;
        const float var = fmaxf(sq[r] * 0.0078125f - mean * mean, 0.f);
        const float inv = rsqrtf(var + 1e-8f);
        s[r] = mean; sq[r] = inv;
    }
#pragma unroll
    for (int t = 0; t < 8; ++t) {
        const int n = t * 16 + nn;
        const float g = lng[n], b = lnb[n];
#pragma unroll
        for (int r = 0; r < 4; ++r) {
            const float v = (y[t][r] - s[r]) * sq[r] * g + b;
            y[t][r] = v;
            hls[(q * 4 + r) * 136 + n] = (ushort_t)f2bf(v);
        }
    }
    __syncthreads();
    {
        const ushort_t* xb = &hls[nn * 136];
#pragma unroll
        for (int f = 0; f < 4; ++f) af[f] = *(const bf16x8*)&xb[f * 32 + q * 8];
    }
    f32x4 acc2[8];
#pragma unroll
    for (int t = 0; t < 8; ++t) acc2[t] = (f32x4){0.f, 0.f, 0.f, 0.f};
    {
        const ushort_t* wbase = c1wb + lane * 8;
#pragma unroll
        for (int t = 0; t < 8; ++t)
#pragma unroll
            for (int f = 0; f < 4; ++f) {
                bf16x8 b = *(const bf16x8*)&wbase[(t * 4 + f) * 512];
                acc2[t] = __builtin_amdgcn_mfma_f32_16x16x32_bf16(af[f], b, acc2[t], 0, 0, 0);
            }
    }
    __syncthreads();
#pragma unroll
    for (int t = 0; t < 8; ++t) {
        const int n = t * 16 + nn;
        const float bi = c1b[n];
#pragma unroll
        for (int r = 0; r < 4; ++r)
            hls[(q * 4 + r) * 136 + n] = (ushort_t)f2bf(fmaxf(acc2[t][r] + bi, 0.f));
    }
    __syncthreads();
    {
        const ushort_t* xb = &hls[nn * 136];
#pragma unroll
        for (int f = 0; f < 4; ++f) af[f] = *(const bf16x8*)&xb[f * 32 + q * 8];
    }
    f32x4 acc3[8];
#pragma unroll
    for (int t = 0; t < 8; ++t) acc3[t] = (f32x4){0.f, 0.f, 0.f, 0.f};
    {
        const ushort_t* wbase = c2wb + lane * 8;
#pragma unroll
        for (int t = 0; t < 8; ++t)
#pragma unroll
            for (int f = 0; f < 4; ++f) {
                bf16x8 b = *(const bf16x8*)&wbase[(t * 4 + f) * 512];
                acc3[t] = __builtin_amdgcn_mfma_f32_16x16x32_bf16(af[f], b, acc3[t], 0, 0, 0);
            }
    }
    float mk[4];
#pragma unroll
    for (int r = 0; r < 4; ++r) mk[r] = validL[m0 + q * 4 + r];

    if constexpr (!LAST) {
#pragma unroll
        for (int t = 0; t < 8; ++t) {
            const int n = t * 16 + nn;
            const float bi = c2b[n];
#pragma unroll
            for (int r = 0; r < 4; ++r) {
                const int row = m0 + q * 4 + r;
                seqs[(size_t)row * 128 + n] = (acc3[t][r] + bi + y[t][r]) * mk[r];
            }
        }
    } else {
        float ov[8][4];
        float s2[4] = {0.f, 0.f, 0.f, 0.f}, q2[4] = {0.f, 0.f, 0.f, 0.f};
#pragma unroll
        for (int t = 0; t < 8; ++t) {
            const int n = t * 16 + nn;
            const float bi = c2b[n];
#pragma unroll
            for (int r = 0; r < 4; ++r) {
                const float v = (acc3[t][r] + bi + y[t][r]) * mk[r];
                ov[t][r] = v;
                s2[r] += v;
                q2[r] += v * v;
            }
        }
#pragma unroll
        for (int m = 1; m < 16; m <<= 1) {
#pragma unroll
            for (int r = 0; r < 4; ++r) {
                s2[r] += __shfl_xor(s2[r], m, 64);
                q2[r] += __shfl_xor(q2[r], m, 64);
            }
        }
#pragma unroll
        for (int r = 0; r < 4; ++r) {
            const float mean = s2[r] * 0.0078125f;
            const float var = fmaxf(q2[r] * 0.0078125f - mean * mean, 0.f);
            const float inv = rsqrtf(var + 1e-8f);
            s2[r] = mean; q2[r] = inv;
        }
        float sp[4] = {0.f, 0.f, 0.f, 0.f}, sn[4] = {0.f, 0.f, 0.f, 0.f};
        int nqr[4], lr[4];
#pragma unroll
        for (int r = 0; r < 4; ++r) {
            const int row = m0 + q * 4 + r;
            nqr[r] = row / 200;
            lr[r] = row - nqr[r] * 200;
        }
#pragma unroll
        for (int t = 0; t < 8; ++t) {
            const int n = t * 16 + nn;
            const float g = lastg[n], b = lastb[n];
#pragma unroll
            for (int r = 0; r < 4; ++r) {
                const int row = m0 + q * 4 + r;
                const float yln = (ov[t][r] - s2[r]) * q2[r] * g + b;
                sp[r] += yln * G[((size_t)nqr[r] * 201 + lr[r] + 1) * 128 + n];
                sn[r] += yln * negt[(size_t)row * 128 + n];
            }
        }
#pragma unroll
        for (int m = 1; m < 16; m <<= 1) {
#pragma unroll
            for (int r = 0; r < 4; ++r) {
                sp[r] += __shfl_xor(sp[r], m, 64);
                sn[r] += __shfl_xor(sn[r], m, 64);
            }
        }
        if (nn == 0) {
#pragma unroll
            for (int r = 0; r < 4; ++r) {
                const int row = m0 + q * 4 + r;
                outp[row] = sp[r] * mk[r];
                outp[25600 + row] = sn[r];
            }
        }
    }
}

// ---------------------------------------------------------------------------
__global__ void reduce_kernel(const float* __restrict__ pInd, const float* __restrict__ pCent,
                              int nblk, const float* __restrict__ validE, int nve,
                              float* __restrict__ outp) {
    __shared__ float a1[256], a2[256], a3[256];
    const int tid = threadIdx.x;
    float si = 0.f, sc = 0.f, nv = 0.f;
    for (int t = tid; t < nblk; t += 256) { si += pInd[t]; sc += pCent[t]; }
    for (int t = tid; t < nve; t += 256) nv += validE[t];
    a1[tid] = si; a2[tid] = sc; a3[tid] = nv;
    __syncthreads();
    for (int s = 128; s > 0; s >>= 1) {
        if (tid < s) { a1[tid] += a1[tid + s]; a2[tid] += a2[tid + s]; a3[tid] += a3[tid + s]; }
        __syncthreads();
    }
    if (tid == 0) { outp[0] = a1[0] / a3[0]; outp[1] = a2[0] / a3[0]; }
}

// ---------------------------------------------------------------------------
// MFMA flash attention, bf16 in/out. Grid = 256 (n,h) x 4 query-tiles.
__global__ __launch_bounds__(256) void attn_kernel(const ushort_t* __restrict__ qp,
                                                   const ushort_t* __restrict__ kp,
                                                   const ushort_t* __restrict__ vp,
                                                   ushort_t* __restrict__ outp) {
    __shared__ ushort_t KsU[2048];
    __shared__ ushort_t VtU[2560];
    __shared__ ushort_t Pb[2560];

    const int tid = threadIdx.x, lane = tid & 63, w = tid >> 6;
    const int b = blockIdx.x;
    const int nh = b >> 2, qt = b & 3;
    const int n = nh >> 1, h = nh & 1;
    const size_t base = (size_t)n * 200 * 128 + (size_t)h * 64;
    const int qw = qt * 64 + w * 16;
    const bool wactive = qw < 200;
    const int q15 = lane & 15, g4 = lane >> 4;
    const int qglob = qw + q15;

    bf16x8 qf[2];
    {
        const int qr = (qglob < 200) ? qglob : 199;
#pragma unroll
        for (int f = 0; f < 2; ++f)
            qf[f] = *(const bf16x8*)&qp[base + (size_t)qr * 128 + f * 32 + g4 * 8];
    }
    f32x4 Oacc[4];
#pragma unroll
    for (int nt = 0; nt < 4; ++nt) Oacc[nt] = (f32x4){0.f, 0.f, 0.f, 0.f};
    float mrun = -1e30f, lrun = 0.f;

    const int kmax = min(200, qt * 64 + 64);
    ushort_t* PbW = Pb + w * 640;

    for (int jt = 0; jt < kmax; jt += 32) {
        __syncthreads();
        {
            const int k = tid >> 3, e0 = (tid & 7) * 8;
            const int krow = jt + k;
            int4 a = make_int4(0, 0, 0, 0);
            if (krow < 200) a = *(const int4*)&kp[base + (size_t)krow * 128 + e0];
            *(int4*)&KsU[(k * 128 + ((e0 * 2) ^ ((k & 7) << 4))) >> 1] = a;
        }
        {
            const int k = tid & 31, e0 = (tid >> 5) * 8;
            const int vrow = jt + k;
            int4 a = make_int4(0, 0, 0, 0);
            if (vrow < 200) a = *(const int4*)&vp[base + (size_t)vrow * 128 + e0];
            VtU[(e0 + 0) * 40 + k] = (ushort_t)((unsigned)a.x & 0xFFFF);
            VtU[(e0 + 1) * 40 + k] = (ushort_t)((unsigned)a.x >> 16);
            VtU[(e0 + 2) * 40 + k] = (ushort_t)((unsigned)a.y & 0xFFFF);
            VtU[(e0 + 3) * 40 + k] = (ushort_t)((unsigned)a.y >> 16);
            VtU[(e0 + 4) * 40 + k] = (ushort_t)((unsigned)a.z & 0xFFFF);
            VtU[(e0 + 5) * 40 + k] = (ushort_t)((unsigned)a.z >> 16);
            VtU[(e0 + 6) * 40 + k] = (ushort_t)((unsigned)a.w & 0xFFFF);
            VtU[(e0 + 7) * 40 + k] = (ushort_t)((unsigned)a.w >> 16);
        }
        __syncthreads();
        if (!wactive) continue;

        f32x4 d0 = {0.f, 0.f, 0.f, 0.f}, d1 = d0;
#pragma unroll
        for (int f = 0; f < 2; ++f) {
            const int ebyte = g4 * 16 + f * 64;
            const int sw = ebyte ^ ((q15 & 7) << 4);
            bf16x8 a0 = *(const bf16x8*)&KsU[(q15 * 128 + sw) >> 1];
            bf16x8 a1 = *(const bf16x8*)&KsU[((q15 + 16) * 128 + sw) >> 1];
            d0 = __builtin_amdgcn_mfma_f32_16x16x32_bf16(a0, qf[f], d0, 0, 0, 0);
            d1 = __builtin_amdgcn_mfma_f32_16x16x32_bf16(a1, qf[f], d1, 0, 0, 0);
        }
        const int kb = jt + g4 * 4;
        float p[8];
        float tmax = -1e30f;
#pragma unroll
        for (int r = 0; r < 4; ++r) {
            const float s0 = (kb + r      <= qglob) ? d0[r] * 0.125f : -1e30f;
            const float s1 = (kb + r + 16 <= qglob) ? d1[r] * 0.125f : -1e30f;
            p[r] = s0; p[r + 4] = s1;
            tmax = fmaxf(tmax, fmaxf(s0, s1));
        }
        tmax = fmaxf(tmax, __shfl_xor(tmax, 16, 64));
        tmax = fmaxf(tmax, __shfl_xor(tmax, 32, 64));
        const float mnew = fmaxf(mrun, tmax);
        const float corr = __expf(mrun - mnew);
        mrun = mnew;
        float tsum = 0.f;
#pragma unroll
        for (int i = 0; i < 8; ++i) {
            float pe = __expf(p[i] - mnew);
            pe = bf2f(f2bf(pe));
            p[i] = pe;
            tsum += pe;
        }
        tsum += __shfl_xor(tsum, 16, 64);
        tsum += __shfl_xor(tsum, 32, 64);
        lrun = lrun * corr + tsum;
        const int kl = g4 * 4;
        *(unsigned*)&PbW[q15 * 40 + kl]          = pk2(p[0], p[1]);
        *(unsigned*)&PbW[q15 * 40 + kl + 2]      = pk2(p[2], p[3]);
        *(unsigned*)&PbW[q15 * 40 + 16 + kl]     = pk2(p[4], p[5]);
        *(unsigned*)&PbW[q15 * 40 + 16 + kl + 2] = pk2(p[6], p[7]);
        asm volatile("" ::: "memory");
        float corr_r[4];
#pragma unroll
        for (int r = 0; r < 4; ++r) corr_r[r] = __shfl(corr, g4 * 4 + r, 64);
#pragma unroll
        for (int nt = 0; nt < 4; ++nt) {
#pragma unroll
            for (int r = 0; r < 4; ++r) Oacc[nt][r] *= corr_r[r];
        }
        bf16x8 pa = *(const bf16x8*)&PbW[q15 * 40 + g4 * 8];
#pragma unroll
        for (int nt = 0; nt < 4; ++nt) {
            bf16x8 vb = *(const bf16x8*)&VtU[(nt * 16 + q15) * 40 + g4 * 8];
            Oacc[nt] = __builtin_amdgcn_mfma_f32_16x16x32_bf16(pa, vb, Oacc[nt], 0, 0, 0);
        }
    }
    if (wactive) {
        float linv[4];
#pragma unroll
        for (int r = 0; r < 4; ++r) linv[r] = 1.f / __shfl(lrun, g4 * 4 + r, 64);
#pragma unroll
        for (int r = 0; r < 4; ++r) {
            const int qg = qw + g4 * 4 + r;
            if (qg < 200) {
#pragma unroll
                for (int nt = 0; nt < 4; ++nt)
                    outp[base + (size_t)qg * 128 + nt * 16 + q15] =
                        (ushort_t)f2bf(Oacc[nt][r] * linv[r]);
            }
        }
    }
}

// ---------------------------------------------------------------------------
extern "C" void kernel_launch(void* const* d_in, const int* in_sizes, int n_in,
                              void* d_out, int out_size, void* d_ws, size_t ws_size,
                              hipStream_t stream) {
    (void)in_sizes; (void)n_in; (void)out_size; (void)ws_size;
    const float* item_emb = (const float*)d_in[0];
    const float* pos_emb  = (const float*)d_in[1];
    const float* W_asp    = (const float*)d_in[2];
    const float* w_weight = (const float*)d_in[3];
    // d_in[4] w_bias: cancels in aspect softmax (shift invariance)
    const float* attn_g = (const float*)d_in[5];
    const float* attn_b = (const float*)d_in[6];
    const float* inW    = (const float*)d_in[7];
    const float* inB    = (const float*)d_in[8];
    const float* outW   = (const float*)d_in[9];
    const float* outB   = (const float*)d_in[10];
    const float* fwd_g  = (const float*)d_in[11];
    const float* fwd_b  = (const float*)d_in[12];
    const float* c1w    = (const float*)d_in[13];
    const float* c1b    = (const float*)d_in[14];
    const float* c2w    = (const float*)d_in[15];
    const float* c2b    = (const float*)d_in[16];
    const float* last_g = (const float*)d_in[17];
    const float* last_b = (const float*)d_in[18];
    const int* log_seqs = (const int*)d_in[20];
    const int* pos_seqs = (const int*)d_in[21];
    const int* neg_seqs = (const int*)d_in[22];

    float* ws = (float*)d_ws;
    const size_t S = (size_t)128 * 201 * 128;  // one (N, 201, 128) fp32 slot
    ushort_t* qp = (ushort_t*)ws;           // slots 0-1: qkv bf16 buffers
    ushort_t* kp = qp + (size_t)25600 * 128;
    float* G     = ws + 2 * S;                      // G||negt contiguous rows
    float* negt  = ws + 3 * S;
    float* seqs  = ws + 4 * S;
    float* Qn    = ws + 5 * S;
    ushort_t* vp    = (ushort_t*)(ws + 6 * S);
    ushort_t* attno = (ushort_t*)(ws + 7 * S);
    ushort_t* wb  = (ushort_t*)(ws + 8 * S);
    ushort_t* Wab  = wb;                    // 262144
    ushort_t* inWb = Wab + 262144;          // 98304
    ushort_t* outWb = inWb + 98304;         // 32768
    ushort_t* c1b_w = outWb + 32768;        // 32768
    ushort_t* c2b_w = c1b_w + 32768;        // 32768
    float* validE = ws + 8 * S + 229376;    // validE||validL contiguous
    float* validL = validE + 128 * 201;
    float* pInd   = validL + 128 * 200;
    float* pCent  = pInd + 1608;
    float* outF   = (float*)d_out;

    cvt_all<<<dim3(1792), dim3(256), 0, stream>>>(W_asp, inW, outW, c1w, c2w, wb);
    aspects2_kernel<<<dim3(3208), dim3(512), 0, stream>>>(
        item_emb, log_seqs, pos_seqs, neg_seqs, Wab, w_weight, pos_emb,
        G, seqs, validE, validL, pInd, pCent, 1608);
    reduce_kernel<<<dim3(1), dim3(256), 0, stream>>>(
        pInd, pCent, 1608, validE, 128 * 201, outF + 51200);

    for (int i = 0; i < 2; ++i) {
        qkv_kernel<<<dim3(1600), dim3(64), 0, stream>>>(
            seqs, inWb + (size_t)i * 3 * 16384, inB + (size_t)i * 384,
            attn_g + i * 128, attn_b + i * 128, Qn, qp, kp, vp);
        attn_kernel<<<dim3(1024), dim3(256), 0, stream>>>(qp, kp, vp, attno);
        if (i == 0) {
            ffn_kernel<0><<<dim3(1600), dim3(64), 0, stream>>>(
                attno, outWb + (size_t)i * 16384, outB + i * 128, Qn,
                fwd_g + i * 128, fwd_b + i * 128,
                c1b_w + (size_t)i * 16384, c1b + i * 128,
                c2b_w + (size_t)i * 16384, c2b + i * 128,
                validL, seqs, nullptr, nullptr, nullptr, nullptr, nullptr);
        } else {
            ffn_kernel<1><<<dim3(1600), dim3(64), 0, stream>>>(
                attno, outWb + (size_t)i * 16384, outB + i * 128, Qn,
                fwd_g + i * 128, fwd_b + i * 128,
                c1b_w + (size_t)i * 16384, c1b + i * 128,
                c2b_w + (size_t)i * 16384, c2b + i * 128,
                validL, nullptr, last_g, last_b, G, negt, outF);
        }
    }
}

// Round 21
// 201.384 us; speedup vs baseline: 1.1547x; 1.1547x over previous
//
#include <hip/hip_runtime.h>
#include <hip/hip_bf16.h>
#include <cstddef>

// Problem constants: N=128, L=200, LE=201, E=128, A=16 aspects, NB=2, H=2, HD=64, TEMP=0.2
typedef __attribute__((ext_vector_type(8))) short bf16x8;
typedef __attribute__((ext_vector_type(4))) float f32x4;
typedef unsigned short ushort_t;

__device__ __forceinline__ short f2bf(float f) {
    __hip_bfloat16 h = __float2bfloat16(f);
    return __builtin_bit_cast(short, h);
}
__device__ __forceinline__ float bf2f(short s) {
    unsigned u = ((unsigned)(unsigned short)s) << 16;
    return __builtin_bit_cast(float, u);
}
__device__ __forceinline__ unsigned pk2(float a, float b) {
    return (unsigned)(unsigned short)f2bf(a) | ((unsigned)(unsigned short)f2bf(b) << 16);
}

// ---------------------------------------------------------------------------
// Convert + permute ALL weight matrices to fragment-major layout.
// Aspect matrices (mat<16) get the residual identity folded in: W' = W + I.
__global__ void cvt_all(const float* __restrict__ s0, const float* __restrict__ s1,
                        const float* __restrict__ s2, const float* __restrict__ s3,
                        const float* __restrict__ s4, ushort_t* __restrict__ dst) {
    const int i = blockIdx.x * 256 + threadIdx.x;   // < 458752
    const int mat = i >> 14;          // 28 matrices of 16384
    const int wm = i & 16383;
    const int blk = wm >> 9;          // t*4 + f
    const int t = blk >> 2, f = blk & 3;
    const int lane = (wm >> 3) & 63;
    const int j = wm & 7;
    const int g4 = lane >> 4, nn = lane & 15;
    const int o = t * 16 + nn;
    const int k = f * 32 + g4 * 8 + j;
    const int srcoff = o * 128 + k;
    const float* src; int mbase;
    if (mat < 16)      { src = s0; mbase = mat; }
    else if (mat < 22) { src = s1; mbase = mat - 16; }
    else if (mat < 24) { src = s2; mbase = mat - 22; }
    else if (mat < 26) { src = s3; mbase = mat - 24; }
    else               { src = s4; mbase = mat - 26; }
    float v = src[(size_t)mbase * 16384 + srcoff];
    if (mat < 16 && o == k) v += 1.f;
    dst[i] = (ushort_t)f2bf(v);
}

// ---------------------------------------------------------------------------
// Fused aspects kernel v7: 32 rows/block (two 16-row tiles), 512 threads.
// Gather fused; residual folded into W'; norms + gate logits via MFMA
// (gram reused for mi); seqs written for kv rows.
__global__ __launch_bounds__(512, 1) void aspects2_kernel(
        const float* __restrict__ item_emb,
        const int* __restrict__ log_seqs, const int* __restrict__ pos_seqs,
        const int* __restrict__ neg_seqs,
        const ushort_t* __restrict__ Wab,
        const float* __restrict__ w_weight,
        const float* __restrict__ pos_emb,
        float* __restrict__ Gout, float* __restrict__ seqs,
        float* __restrict__ validE, float* __restrict__ validL,
        float* __restrict__ pInd, float* __restrict__ pCent,
        int nLossBlocks) {
    __shared__ ushort_t rsb[32 * 2184];    // v = x@W'^T, bf16 (139.8 KB)
    __shared__ ushort_t xsb[32 * 136];     // x bf16 (8.7 KB)
    __shared__ ushort_t wal_b[128];        // w_a bf16
    __shared__ int sidx[32];
    __shared__ float s_red[512];
    __shared__ float s_lg[512];
    __shared__ float s_pos[512];
    __shared__ float vld[32];
    __shared__ float centw[32];
    __shared__ float miw[32];

    const int tid = threadIdx.x;
    const int row0 = blockIdx.x * 32;
    const bool losses = (int)blockIdx.x < nLossBlocks;
    const int lane = tid & 63, w = tid >> 6;
    const int g4 = lane >> 4, nn = lane & 15;

    if (tid < 32) {
        const int rg = row0 + tid;
        int si; float vl;
        if (rg < 25728) {
            const int nq = rg / 201, l = rg % 201;
            if (l < 200) { si = log_seqs[nq * 200 + l]; vl = (si != 0) ? 1.f : 0.f; }
            else { vl = (log_seqs[nq * 200 + 199] != 0) ? 1.f : 0.f; si = pos_seqs[nq * 200 + 199]; }
            validE[rg] = vl;
        } else {
            const int rr = rg - 25728;
            vl = (log_seqs[rr] != 0) ? 1.f : 0.f;
            si = neg_seqs[rr];
            validL[rr] = vl;
        }
        sidx[tid] = si;
        vld[tid] = vl;
    }
    if (tid < 128) wal_b[tid] = (ushort_t)f2bf(w_weight[128 + tid]);
    __syncthreads();

    {
        const int r = tid >> 4, c8 = (tid & 15) * 8;
        const float vl = vld[r];
        const float* px = &item_emb[(size_t)sidx[r] * 128 + c8];
        const float4 a = *(const float4*)px;
        const float4 b = *(const float4*)(px + 4);
        *(int2*)&xsb[r * 136 + c8] = make_int2(
            (int)pk2(a.x * vl, a.y * vl), (int)pk2(a.z * vl, a.w * vl));
        *(int2*)&xsb[r * 136 + c8 + 4] = make_int2(
            (int)pk2(b.x * vl, b.y * vl), (int)pk2(b.z * vl, b.w * vl));
    }
    __syncthreads();

    bf16x8 xf0[4], xf1[4], waf[4];
#pragma unroll
    for (int f = 0; f < 4; ++f) {
        xf0[f] = *(const bf16x8*)&xsb[nn * 136 + f * 32 + g4 * 8];
        xf1[f] = *(const bf16x8*)&xsb[(nn + 16) * 136 + f * 32 + g4 * 8];
        waf[f] = *(const bf16x8*)&wal_b[f * 32 + g4 * 8];
    }

    for (int al = 0; al < 2; ++al) {
        const int a = w * 2 + al;
        const ushort_t* wbase = Wab + (size_t)a * 16384 + lane * 8;
#pragma unroll
        for (int t = 0; t < 8; ++t) {
            f32x4 d0 = {0.f, 0.f, 0.f, 0.f}, d1 = d0;
#pragma unroll
            for (int f = 0; f < 4; ++f) {
                bf16x8 wf = *(const bf16x8*)&wbase[(t * 4 + f) * 512];
                d0 = __builtin_amdgcn_mfma_f32_16x16x32_bf16(wf, xf0[f], d0, 0, 0, 0);
                d1 = __builtin_amdgcn_mfma_f32_16x16x32_bf16(wf, xf1[f], d1, 0, 0, 0);
            }
            const int o0 = t * 16 + g4 * 4;
            *(int2*)&rsb[nn * 2184 + a * 136 + o0] = make_int2(
                (int)pk2(d0[0], d0[1]), (int)pk2(d0[2], d0[3]));
            *(int2*)&rsb[(nn + 16) * 2184 + a * 136 + o0] = make_int2(
                (int)pk2(d1[0], d1[1]), (int)pk2(d1[2], d1[3]));
        }
    }
    __syncthreads();

    f32x4 gram0 = {0.f,0.f,0.f,0.f}, gram1 = gram0, gram2 = gram0, gram3 = gram0;
#pragma unroll
    for (int rl = 0; rl < 4; ++rl) {
        const int row = w * 4 + rl;
        f32x4 dgr = {0.f, 0.f, 0.f, 0.f}, dlp = dgr;
#pragma unroll
        for (int f = 0; f < 4; ++f) {
            bf16x8 fr = *(const bf16x8*)&rsb[row * 2184 + nn * 136 + f * 32 + g4 * 8];
            dgr = __builtin_amdgcn_mfma_f32_16x16x32_bf16(fr, fr, dgr, 0, 0, 0);
            dlp = __builtin_amdgcn_mfma_f32_16x16x32_bf16(fr, waf[f], dlp, 0, 0, 0);
        }
        if (rl == 0) gram0 = dgr; else if (rl == 1) gram1 = dgr;
        else if (rl == 2) gram2 = dgr; else gram3 = dgr;
        if (g4 == (nn >> 2)) s_red[row * 16 + nn] = dgr[nn & 3];
        if (nn == 0) {
#pragma unroll
            for (int r = 0; r < 4; ++r) s_lg[row * 16 + g4 * 4 + r] = dlp[r];
        }
    }
    __syncthreads();

    {
        const float nrm = sqrtf(s_red[tid]);
        const float inv1 = 1.f / (nrm + 1e-8f);
        const float n2 = nrm * inv1;
        const float sg = inv1 / (n2 + 1e-8f);
        const float ts = n2 / (n2 + 1e-8f);
        const float logit = s_lg[tid] * inv1;
        float mx = logit;
#pragma unroll
        for (int m = 1; m < 16; m <<= 1) mx = fmaxf(mx, __shfl_xor(mx, m, 16));
        const float e = __expf(logit - mx);
        float ssum = e;
#pragma unroll
        for (int m = 1; m < 16; m <<= 1) ssum += __shfl_xor(ssum, m, 16);
        s_red[tid] = sg;
        s_pos[tid] = ts * ts * 5.f;
        s_lg[tid] = (e / ssum + 0.0625f) * inv1;
    }
    __syncthreads();

    {
        const int row = tid >> 4, ol = tid & 15, o8 = ol * 8;
        float g[8] = {0.f, 0.f, 0.f, 0.f, 0.f, 0.f, 0.f, 0.f};
        float sr[8] = {0.f, 0.f, 0.f, 0.f, 0.f, 0.f, 0.f, 0.f};
#pragma unroll
        for (int a = 0; a < 16; ++a) {
            const bf16x8 vb = *(const bf16x8*)&rsb[row * 2184 + a * 136 + o8];
            const float gw = s_lg[row * 16 + a];
#pragma unroll
            for (int j = 0; j < 8; ++j) {
                const float v = bf2f(vb[j]);
                g[j] += v * gw;
                if (losses) sr[j] += v;
            }
        }
        float* go = &Gout[(size_t)(row0 + row) * 128 + o8];
        *(float4*)go       = make_float4(g[0], g[1], g[2], g[3]);
        *(float4*)(go + 4) = make_float4(g[4], g[5], g[6], g[7]);
        if (losses) {
            const int rg = row0 + row;
            const int nq = rg / 201, l = rg % 201;
            if (l < 200) {
                const float4 p0 = *(const float4*)&pos_emb[l * 128 + o8];
                const float4 p1 = *(const float4*)&pos_emb[l * 128 + o8 + 4];
                const float vv = vld[row];
                float* so = &seqs[(size_t)(nq * 200 + l) * 128 + o8];
                const float SQ = 11.313708498984761f;
                *(float4*)so = make_float4((g[0] * SQ + p0.x) * vv, (g[1] * SQ + p0.y) * vv,
                                           (g[2] * SQ + p0.z) * vv, (g[3] * SQ + p0.w) * vv);
                *(float4*)(so + 4) = make_float4((g[4] * SQ + p1.x) * vv, (g[5] * SQ + p1.y) * vv,
                                                 (g[6] * SQ + p1.z) * vv, (g[7] * SQ + p1.w) * vv);
            }
            const bf16x8 xb = *(const bf16x8*)&xsb[row * 136 + o8];
            float c = 0.f;
#pragma unroll
            for (int j = 0; j < 8; ++j) {
                const float dd = 2.f * bf2f(xb[j]) - sr[j] * 0.0625f;
                c += dd * dd;
            }
            c += __shfl_xor(c, 1, 64);
            c += __shfl_xor(c, 2, 64);
            c += __shfl_xor(c, 4, 64);
            c += __shfl_xor(c, 8, 64);
            if (ol == 0) centw[row] = sqrtf(c) * vld[row];
        }
    }

    if (losses) {
#pragma unroll
        for (int rl = 0; rl < 4; ++rl) {
            const int row = w * 4 + rl;
            const f32x4 dd = (rl == 0) ? gram0 : (rl == 1) ? gram1 : (rl == 2) ? gram2 : gram3;
            const float sgb = s_red[row * 16 + nn];
            float mis = 0.f;
#pragma unroll
            for (int r = 0; r < 4; ++r) {
                const int a = g4 * 4 + r;
                const float sga = s_red[row * 16 + a];
                float eb = __expf(5.f * dd[r] * sga * sgb);
#pragma unroll
                for (int m = 1; m < 16; m <<= 1) eb += __shfl_xor(eb, m, 16);
                mis += -(s_pos[row * 16 + a] - logf(eb));
            }
            mis += __shfl_xor(mis, 16, 64);
            mis += __shfl_xor(mis, 32, 64);
            if (lane == 0) miw[row] = mis * vld[row];
        }
        __syncthreads();
        if (tid == 0) {
            float si = 0.f, sc = 0.f;
#pragma unroll
            for (int r = 0; r < 32; ++r) { si += miw[r]; sc += centw[r]; }
            pInd[blockIdx.x] = si;
            pCent[blockIdx.x] = sc;
        }
    }
}

// ---------------------------------------------------------------------------
// Fused QKV projection: ONE WAVE per 16-row tile (grid 1600) for machine fill.
__global__ __launch_bounds__(64) void qkv_kernel(const float* __restrict__ X,
                                                 const ushort_t* __restrict__ W3,
                                                 const float* __restrict__ b3,
                                                 const float* __restrict__ lng,
                                                 const float* __restrict__ lnb,
                                                 float* __restrict__ Xn,
                                                 ushort_t* __restrict__ qo,
                                                 ushort_t* __restrict__ ko,
                                                 ushort_t* __restrict__ vo) {
    const int lane = threadIdx.x & 63;
    const int q = lane >> 4, nn = lane & 15;
    const int m0 = blockIdx.x * 16;
    float xv[4][8];
    float s = 0.f, sq = 0.f;
    const float* xr = &X[(size_t)(m0 + nn) * 128];
#pragma unroll
    for (int f = 0; f < 4; ++f) {
        const float4 a = *(const float4*)&xr[f * 32 + q * 8];
        const float4 b = *(const float4*)&xr[f * 32 + q * 8 + 4];
        xv[f][0] = a.x; xv[f][1] = a.y; xv[f][2] = a.z; xv[f][3] = a.w;
        xv[f][4] = b.x; xv[f][5] = b.y; xv[f][6] = b.z; xv[f][7] = b.w;
        s += (a.x + a.y) + (a.z + a.w) + (b.x + b.y) + (b.z + b.w);
        sq += (a.x * a.x + a.y * a.y) + (a.z * a.z + a.w * a.w)
            + (b.x * b.x + b.y * b.y) + (b.z * b.z + b.w * b.w);
    }
    bf16x8 afr[4];   // raw (K/V operand)
#pragma unroll
    for (int f = 0; f < 4; ++f) {
        bf16x8 v;
#pragma unroll
        for (int j = 0; j < 8; ++j) v[j] = f2bf(xv[f][j]);
        afr[f] = v;
    }
    s += __shfl_xor(s, 16, 64);  s += __shfl_xor(s, 32, 64);
    sq += __shfl_xor(sq, 16, 64); sq += __shfl_xor(sq, 32, 64);
    const float mean = s * 0.0078125f;
    const float var = fmaxf(sq * 0.0078125f - mean * mean, 0.f);
    const float inv = rsqrtf(var + 1e-8f);
    bf16x8 afq[4];   // normalized (Q operand)
#pragma unroll
    for (int f = 0; f < 4; ++f) {
        const int c0 = f * 32 + q * 8;
        const float4 ga = *(const float4*)&lng[c0];
        const float4 gb = *(const float4*)&lng[c0 + 4];
        const float4 ba = *(const float4*)&lnb[c0];
        const float4 bb = *(const float4*)&lnb[c0 + 4];
        float y[8];
        y[0] = (xv[f][0] - mean) * inv * ga.x + ba.x;
        y[1] = (xv[f][1] - mean) * inv * ga.y + ba.y;
        y[2] = (xv[f][2] - mean) * inv * ga.z + ba.z;
        y[3] = (xv[f][3] - mean) * inv * ga.w + ba.w;
        y[4] = (xv[f][4] - mean) * inv * gb.x + bb.x;
        y[5] = (xv[f][5] - mean) * inv * gb.y + bb.y;
        y[6] = (xv[f][6] - mean) * inv * gb.z + bb.z;
        y[7] = (xv[f][7] - mean) * inv * gb.w + bb.w;
        float* xo = &Xn[(size_t)(m0 + nn) * 128 + c0];
        *(float4*)xo       = make_float4(y[0], y[1], y[2], y[3]);
        *(float4*)(xo + 4) = make_float4(y[4], y[5], y[6], y[7]);
        bf16x8 v;
#pragma unroll
        for (int j = 0; j < 8; ++j) v[j] = f2bf(y[j]);
        afq[f] = v;
    }
    ushort_t* const outs[3] = {qo, ko, vo};
#pragma unroll
    for (int mi = 0; mi < 3; ++mi) {
        const ushort_t* wbase = W3 + (size_t)mi * 16384 + lane * 8;
        f32x4 acc[8];
#pragma unroll
        for (int t = 0; t < 8; ++t) acc[t] = (f32x4){0.f, 0.f, 0.f, 0.f};
#pragma unroll
        for (int t = 0; t < 8; ++t) {
#pragma unroll
            for (int f = 0; f < 4; ++f) {
                bf16x8 b = *(const bf16x8*)&wbase[(t * 4 + f) * 512];
                acc[t] = __builtin_amdgcn_mfma_f32_16x16x32_bf16(
                    (mi == 0) ? afq[f] : afr[f], b, acc[t], 0, 0, 0);
            }
        }
        const float* bi = b3 + mi * 128;
        ushort_t* outp = outs[mi];
#pragma unroll
        for (int t = 0; t < 8; ++t) {
            const int n = t * 16 + nn;
            const float bv = bi[n];
#pragma unroll
            for (int r = 0; r < 4; ++r) {
                const int row = m0 + q * 4 + r;
                outp[(size_t)row * 128 + n] = (ushort_t)f2bf(acc[t][r] + bv);
            }
        }
    }
}

// ---------------------------------------------------------------------------
// Fused FFN block, ONE WAVE per 16-row tile (grid 1600).
// LAST=1: final LN + pos/neg logit dots fused (no seqs write).
template <int LAST>
__global__ __launch_bounds__(64) void ffn_kernel(const ushort_t* __restrict__ attno,
                                                 const ushort_t* __restrict__ outWb,
                                                 const float* __restrict__ outB,
                                                 const float* __restrict__ resQn,
                                                 const float* __restrict__ lng,
                                                 const float* __restrict__ lnb,
                                                 const ushort_t* __restrict__ c1wb,
                                                 const float* __restrict__ c1b,
                                                 const ushort_t* __restrict__ c2wb,
                                                 const float* __restrict__ c2b,
                                                 const float* __restrict__ validL,
                                                 float* __restrict__ seqs,
                                                 const float* __restrict__ lastg,
                                                 const float* __restrict__ lastb,
                                                 const float* __restrict__ G,
                                                 const float* __restrict__ negt,
                                                 float* __restrict__ outp) {
    __shared__ ushort_t hls[16 * 136];   // 4.4 KB, holds y then h (bf16)
    const int lane = threadIdx.x & 63;
    const int q = lane >> 4, nn = lane & 15;
    const int m0 = blockIdx.x * 16;

    bf16x8 af[4];
    {
        const ushort_t* xb = &attno[(size_t)(m0 + nn) * 128];
#pragma unroll
        for (int f = 0; f < 4; ++f) af[f] = *(const bf16x8*)&xb[f * 32 + q * 8];
    }
    f32x4 acc[8];
#pragma unroll
    for (int t = 0; t < 8; ++t) acc[t] = (f32x4){0.f, 0.f, 0.f, 0.f};
    {
        const ushort_t* wbase = outWb + lane * 8;
#pragma unroll
        for (int t = 0; t < 8; ++t)
#pragma unroll
            for (int f = 0; f < 4; ++f) {
                bf16x8 b = *(const bf16x8*)&wbase[(t * 4 + f) * 512];
                acc[t] = __builtin_amdgcn_mfma_f32_16x16x32_bf16(af[f], b, acc[t], 0, 0, 0);
            }
    }
    float y[8][4];
    float s[4] = {0.f, 0.f, 0.f, 0.f}, sq[4] = {0.f, 0.f, 0.f, 0.f};
#pragma unroll
    for (int t = 0; t < 8; ++t) {
        const int n = t * 16 + nn;
        const float bi = outB[n];
#pragma unroll
        for (int r = 0; r < 4; ++r) {
            const float v = acc[t][r] + bi + resQn[(size_t)(m0 + q * 4 + r) * 128 + n];
            y[t][r] = v;
            s[r] += v;
            sq[r] += v * v;
        }
    }
#pragma unroll
    for (int m = 1; m < 16; m <<= 1) {
#pragma unroll
        for (int r = 0; r < 4; ++r) {
            s[r] += __shfl_xor(s[r], m, 64);
            sq[r] += __shfl_xor(sq[r], m, 64);
        }
    }
#pragma unroll
    for (int r = 0; r < 4; ++r) {
        const float mean = s[r] * 0.0078125f;
        const float var = fmaxf(sq[r] * 0.0078125f - mean * mean, 0.f);
        const float inv = rsqrtf(var + 1e-8f);
        s[r] = mean; sq[r] = inv;
    }
#pragma unroll
    for (int t = 0; t < 8; ++t) {
        const int n = t * 16 + nn;
        const float g = lng[n], b = lnb[n];
#pragma unroll
        for (int r = 0; r < 4; ++r) {
            const float v = (y[t][r] - s[r]) * sq[r] * g + b;
            y[t][r] = v;
            hls[(q * 4 + r) * 136 + n] = (ushort_t)f2bf(v);
        }
    }
    __syncthreads();
    {
        const ushort_t* xb = &hls[nn * 136];
#pragma unroll
        for (int f = 0; f < 4; ++f) af[f] = *(const bf16x8*)&xb[f * 32 + q * 8];
    }
    f32x4 acc2[8];
#pragma unroll
    for (int t = 0; t < 8; ++t) acc2[t] = (f32x4){0.f, 0.f, 0.f, 0.f};
    {
        const ushort_t* wbase = c1wb + lane * 8;
#pragma unroll
        for (int t = 0; t < 8; ++t)
#pragma unroll
            for (int f = 0; f < 4; ++f) {
                bf16x8 b = *(const bf16x8*)&wbase[(t * 4 + f) * 512];
                acc2[t] = __builtin_amdgcn_mfma_f32_16x16x32_bf16(af[f], b, acc2[t], 0, 0, 0);
            }
    }
    __syncthreads();
#pragma unroll
    for (int t = 0; t < 8; ++t) {
        const int n = t * 16 + nn;
        const float bi = c1b[n];
#pragma unroll
        for (int r = 0; r < 4; ++r)
            hls[(q * 4 + r) * 136 + n] = (ushort_t)f2bf(fmaxf(acc2[t][r] + bi, 0.f));
    }
    __syncthreads();
    {
        const ushort_t* xb = &hls[nn * 136];
#pragma unroll
        for (int f = 0; f < 4; ++f) af[f] = *(const bf16x8*)&xb[f * 32 + q * 8];
    }
    f32x4 acc3[8];
#pragma unroll
    for (int t = 0; t < 8; ++t) acc3[t] = (f32x4){0.f, 0.f, 0.f, 0.f};
    {
        const ushort_t* wbase = c2wb + lane * 8;
#pragma unroll
        for (int t = 0; t < 8; ++t)
#pragma unroll
            for (int f = 0; f < 4; ++f) {
                bf16x8 b = *(const bf16x8*)&wbase[(t * 4 + f) * 512];
                acc3[t] = __builtin_amdgcn_mfma_f32_16x16x32_bf16(af[f], b, acc3[t], 0, 0, 0);
            }
    }
    float mk[4];
#pragma unroll
    for (int r = 0; r < 4; ++r) mk[r] = validL[m0 + q * 4 + r];

    if constexpr (!LAST) {
#pragma unroll
        for (int t = 0; t < 8; ++t) {
            const int n = t * 16 + nn;
            const float bi = c2b[n];
#pragma unroll
            for (int r = 0; r < 4; ++r) {
                const int row = m0 + q * 4 + r;
                seqs[(size_t)row * 128 + n] = (acc3[t][r] + bi + y[t][r]) * mk[r];
            }
        }
    } else {
        float ov[8][4];
        float s2[4] = {0.f, 0.f, 0.f, 0.f}, q2[4] = {0.f, 0.f, 0.f, 0.f};
#pragma unroll
        for (int t = 0; t < 8; ++t) {
            const int n = t * 16 + nn;
            const float bi = c2b[n];
#pragma unroll
            for (int r = 0; r < 4; ++r) {
                const float v = (acc3[t][r] + bi + y[t][r]) * mk[r];
                ov[t][r] = v;
                s2[r] += v;
                q2[r] += v * v;
            }
        }
#pragma unroll
        for (int m = 1; m < 16; m <<= 1) {
#pragma unroll
            for (int r = 0; r < 4; ++r) {
                s2[r] += __shfl_xor(s2[r], m, 64);
                q2[r] += __shfl_xor(q2[r], m, 64);
            }
        }
#pragma unroll
        for (int r = 0; r < 4; ++r) {
            const float mean = s2[r] * 0.0078125f;
            const float var = fmaxf(q2[r] * 0.0078125f - mean * mean, 0.f);
            const float inv = rsqrtf(var + 1e-8f);
            s2[r] = mean; q2[r] = inv;
        }
        float sp[4] = {0.f, 0.f, 0.f, 0.f}, sn[4] = {0.f, 0.f, 0.f, 0.f};
        int nqr[4], lr[4];
#pragma unroll
        for (int r = 0; r < 4; ++r) {
            const int row = m0 + q * 4 + r;
            nqr[r] = row / 200;
            lr[r] = row - nqr[r] * 200;
        }
#pragma unroll
        for (int t = 0; t < 8; ++t) {
            const int n = t * 16 + nn;
            const float g = lastg[n], b = lastb[n];
#pragma unroll
            for (int r = 0; r < 4; ++r) {
                const int row = m0 + q * 4 + r;
                const float yln = (ov[t][r] - s2[r]) * q2[r] * g + b;
                sp[r] += yln * G[((size_t)nqr[r] * 201 + lr[r] + 1) * 128 + n];
                sn[r] += yln * negt[(size_t)row * 128 + n];
            }
        }
#pragma unroll
        for (int m = 1; m < 16; m <<= 1) {
#pragma unroll
            for (int r = 0; r < 4; ++r) {
                sp[r] += __shfl_xor(sp[r], m, 64);
                sn[r] += __shfl_xor(sn[r], m, 64);
            }
        }
        if (nn == 0) {
#pragma unroll
            for (int r = 0; r < 4; ++r) {
                const int row = m0 + q * 4 + r;
                outp[row] = sp[r] * mk[r];
                outp[25600 + row] = sn[r];
            }
        }
    }
}

// ---------------------------------------------------------------------------
__global__ void reduce_kernel(const float* __restrict__ pInd, const float* __restrict__ pCent,
                              int nblk, const float* __restrict__ validE, int nve,
                              float* __restrict__ outp) {
    __shared__ float a1[256], a2[256], a3[256];
    const int tid = threadIdx.x;
    float si = 0.f, sc = 0.f, nv = 0.f;
    for (int t = tid; t < nblk; t += 256) { si += pInd[t]; sc += pCent[t]; }
    for (int t = tid; t < nve; t += 256) nv += validE[t];
    a1[tid] = si; a2[tid] = sc; a3[tid] = nv;
    __syncthreads();
    for (int s = 128; s > 0; s >>= 1) {
        if (tid < s) { a1[tid] += a1[tid + s]; a2[tid] += a2[tid + s]; a3[tid] += a3[tid + s]; }
        __syncthreads();
    }
    if (tid == 0) { outp[0] = a1[0] / a3[0]; outp[1] = a2[0] / a3[0]; }
}

// ---------------------------------------------------------------------------
// MFMA flash attention, bf16 in/out. Grid = 256 (n,h) x 4 query-tiles.
__global__ __launch_bounds__(256) void attn_kernel(const ushort_t* __restrict__ qp,
                                                   const ushort_t* __restrict__ kp,
                                                   const ushort_t* __restrict__ vp,
                                                   ushort_t* __restrict__ outp) {
    __shared__ ushort_t KsU[2048];
    __shared__ ushort_t VtU[2560];
    __shared__ ushort_t Pb[2560];

    const int tid = threadIdx.x, lane = tid & 63, w = tid >> 6;
    const int b = blockIdx.x;
    const int nh = b >> 2, qt = b & 3;
    const int n = nh >> 1, h = nh & 1;
    const size_t base = (size_t)n * 200 * 128 + (size_t)h * 64;
    const int qw = qt * 64 + w * 16;
    const bool wactive = qw < 200;
    const int q15 = lane & 15, g4 = lane >> 4;
    const int qglob = qw + q15;

    bf16x8 qf[2];
    {
        const int qr = (qglob < 200) ? qglob : 199;
#pragma unroll
        for (int f = 0; f < 2; ++f)
            qf[f] = *(const bf16x8*)&qp[base + (size_t)qr * 128 + f * 32 + g4 * 8];
    }
    f32x4 Oacc[4];
#pragma unroll
    for (int nt = 0; nt < 4; ++nt) Oacc[nt] = (f32x4){0.f, 0.f, 0.f, 0.f};
    float mrun = -1e30f, lrun = 0.f;

    const int kmax = min(200, qt * 64 + 64);
    ushort_t* PbW = Pb + w * 640;

    for (int jt = 0; jt < kmax; jt += 32) {
        __syncthreads();
        {
            const int k = tid >> 3, e0 = (tid & 7) * 8;
            const int krow = jt + k;
            int4 a = make_int4(0, 0, 0, 0);
            if (krow < 200) a = *(const int4*)&kp[base + (size_t)krow * 128 + e0];
            *(int4*)&KsU[(k * 128 + ((e0 * 2) ^ ((k & 7) << 4))) >> 1] = a;
        }
        {
            const int k = tid & 31, e0 = (tid >> 5) * 8;
            const int vrow = jt + k;
            int4 a = make_int4(0, 0, 0, 0);
            if (vrow < 200) a = *(const int4*)&vp[base + (size_t)vrow * 128 + e0];
            VtU[(e0 + 0) * 40 + k] = (ushort_t)((unsigned)a.x & 0xFFFF);
            VtU[(e0 + 1) * 40 + k] = (ushort_t)((unsigned)a.x >> 16);
            VtU[(e0 + 2) * 40 + k] = (ushort_t)((unsigned)a.y & 0xFFFF);
            VtU[(e0 + 3) * 40 + k] = (ushort_t)((unsigned)a.y >> 16);
            VtU[(e0 + 4) * 40 + k] = (ushort_t)((unsigned)a.z & 0xFFFF);
            VtU[(e0 + 5) * 40 + k] = (ushort_t)((unsigned)a.z >> 16);
            VtU[(e0 + 6) * 40 + k] = (ushort_t)((unsigned)a.w & 0xFFFF);
            VtU[(e0 + 7) * 40 + k] = (ushort_t)((unsigned)a.w >> 16);
        }
        __syncthreads();
        if (!wactive) continue;

        f32x4 d0 = {0.f, 0.f, 0.f, 0.f}, d1 = d0;
#pragma unroll
        for (int f = 0; f < 2; ++f) {
            const int ebyte = g4 * 16 + f * 64;
            const int sw = ebyte ^ ((q15 & 7) << 4);
            bf16x8 a0 = *(const bf16x8*)&KsU[(q15 * 128 + sw) >> 1];
            bf16x8 a1 = *(const bf16x8*)&KsU[((q15 + 16) * 128 + sw) >> 1];
            d0 = __builtin_amdgcn_mfma_f32_16x16x32_bf16(a0, qf[f], d0, 0, 0, 0);
            d1 = __builtin_amdgcn_mfma_f32_16x16x32_bf16(a1, qf[f], d1, 0, 0, 0);
        }
        const int kb = jt + g4 * 4;
        float p[8];
        float tmax = -1e30f;
#pragma unroll
        for (int r = 0; r < 4; ++r) {
            const float s0 = (kb + r      <= qglob) ? d0[r] * 0.125f : -1e30f;
            const float s1 = (kb + r + 16 <= qglob) ? d1[r] * 0.125f : -1e30f;
            p[r] = s0; p[r + 4] = s1;
            tmax = fmaxf(tmax, fmaxf(s0, s1));
        }
        tmax = fmaxf(tmax, __shfl_xor(tmax, 16, 64));
        tmax = fmaxf(tmax, __shfl_xor(tmax, 32, 64));
        const float mnew = fmaxf(mrun, tmax);
        const float corr = __expf(mrun - mnew);
        mrun = mnew;
        float tsum = 0.f;
#pragma unroll
        for (int i = 0; i < 8; ++i) {
            float pe = __expf(p[i] - mnew);
            pe = bf2f(f2bf(pe));
            p[i] = pe;
            tsum += pe;
        }
        tsum += __shfl_xor(tsum, 16, 64);
        tsum += __shfl_xor(tsum, 32, 64);
        lrun = lrun * corr + tsum;
        const int kl = g4 * 4;
        *(unsigned*)&PbW[q15 * 40 + kl]          = pk2(p[0], p[1]);
        *(unsigned*)&PbW[q15 * 40 + kl + 2]      = pk2(p[2], p[3]);
        *(unsigned*)&PbW[q15 * 40 + 16 + kl]     = pk2(p[4], p[5]);
        *(unsigned*)&PbW[q15 * 40 + 16 + kl + 2] = pk2(p[6], p[7]);
        asm volatile("" ::: "memory");
        float corr_r[4];
#pragma unroll
        for (int r = 0; r < 4; ++r) corr_r[r] = __shfl(corr, g4 * 4 + r, 64);
#pragma unroll
        for (int nt = 0; nt < 4; ++nt) {
#pragma unroll
            for (int r = 0; r < 4; ++r) Oacc[nt][r] *= corr_r[r];
        }
        bf16x8 pa = *(const bf16x8*)&PbW[q15 * 40 + g4 * 8];
#pragma unroll
        for (int nt = 0; nt < 4; ++nt) {
            bf16x8 vb = *(const bf16x8*)&VtU[(nt * 16 + q15) * 40 + g4 * 8];
            Oacc[nt] = __builtin_amdgcn_mfma_f32_16x16x32_bf16(pa, vb, Oacc[nt], 0, 0, 0);
        }
    }
    if (wactive) {
        float linv[4];
#pragma unroll
        for (int r = 0; r < 4; ++r) linv[r] = 1.f / __shfl(lrun, g4 * 4 + r, 64);
#pragma unroll
        for (int r = 0; r < 4; ++r) {
            const int qg = qw + g4 * 4 + r;
            if (qg < 200) {
#pragma unroll
                for (int nt = 0; nt < 4; ++nt)
                    outp[base + (size_t)qg * 128 + nt * 16 + q15] =
                        (ushort_t)f2bf(Oacc[nt][r] * linv[r]);
            }
        }
    }
}

// ---------------------------------------------------------------------------
extern "C" void kernel_launch(void* const* d_in, const int* in_sizes, int n_in,
                              void* d_out, int out_size, void* d_ws, size_t ws_size,
                              hipStream_t stream) {
    (void)in_sizes; (void)n_in; (void)out_size; (void)ws_size;
    const float* item_emb = (const float*)d_in[0];
    const float* pos_emb  = (const float*)d_in[1];
    const float* W_asp    = (const float*)d_in[2];
    const float* w_weight = (const float*)d_in[3];
    // d_in[4] w_bias: cancels in aspect softmax (shift invariance)
    const float* attn_g = (const float*)d_in[5];
    const float* attn_b = (const float*)d_in[6];
    const float* inW    = (const float*)d_in[7];
    const float* inB    = (const float*)d_in[8];
    const float* outW   = (const float*)d_in[9];
    const float* outB   = (const float*)d_in[10];
    const float* fwd_g  = (const float*)d_in[11];
    const float* fwd_b  = (const float*)d_in[12];
    const float* c1w    = (const float*)d_in[13];
    const float* c1b    = (const float*)d_in[14];
    const float* c2w    = (const float*)d_in[15];
    const float* c2b    = (const float*)d_in[16];
    const float* last_g = (const float*)d_in[17];
    const float* last_b = (const float*)d_in[18];
    const int* log_seqs = (const int*)d_in[20];
    const int* pos_seqs = (const int*)d_in[21];
    const int* neg_seqs = (const int*)d_in[22];

    float* ws = (float*)d_ws;
    const size_t S = (size_t)128 * 201 * 128;  // one (N, 201, 128) fp32 slot
    ushort_t* qp = (ushort_t*)ws;           // slots 0-1: qkv bf16 buffers
    ushort_t* kp = qp + (size_t)25600 * 128;
    float* G     = ws + 2 * S;                      // G||negt contiguous rows
    float* negt  = ws + 3 * S;
    float* seqs  = ws + 4 * S;
    float* Qn    = ws + 5 * S;
    ushort_t* vp    = (ushort_t*)(ws + 6 * S);
    ushort_t* attno = (ushort_t*)(ws + 7 * S);
    ushort_t* wb  = (ushort_t*)(ws + 8 * S);
    ushort_t* Wab  = wb;                    // 262144
    ushort_t* inWb = Wab + 262144;          // 98304
    ushort_t* outWb = inWb + 98304;         // 32768
    ushort_t* c1b_w = outWb + 32768;        // 32768
    ushort_t* c2b_w = c1b_w + 32768;        // 32768
    float* validE = ws + 8 * S + 229376;    // validE||validL contiguous
    float* validL = validE + 128 * 201;
    float* pInd   = validL + 128 * 200;
    float* pCent  = pInd + 804;
    float* outF   = (float*)d_out;

    cvt_all<<<dim3(1792), dim3(256), 0, stream>>>(W_asp, inW, outW, c1w, c2w, wb);
    aspects2_kernel<<<dim3(1604), dim3(512), 0, stream>>>(
        item_emb, log_seqs, pos_seqs, neg_seqs, Wab, w_weight, pos_emb,
        G, seqs, validE, validL, pInd, pCent, 804);
    reduce_kernel<<<dim3(1), dim3(256), 0, stream>>>(
        pInd, pCent, 804, validE, 128 * 201, outF + 51200);

    for (int i = 0; i < 2; ++i) {
        qkv_kernel<<<dim3(1600), dim3(64), 0, stream>>>(
            seqs, inWb + (size_t)i * 3 * 16384, inB + (size_t)i * 384,
            attn_g + i * 128, attn_b + i * 128, Qn, qp, kp, vp);
        attn_kernel<<<dim3(1024), dim3(256), 0, stream>>>(qp, kp, vp, attno);
        if (i == 0) {
            ffn_kernel<0><<<dim3(1600), dim3(64), 0, stream>>>(
                attno, outWb + (size_t)i * 16384, outB + i * 128, Qn,
                fwd_g + i * 128, fwd_b + i * 128,
                c1b_w + (size_t)i * 16384, c1b + i * 128,
                c2b_w + (size_t)i * 16384, c2b + i * 128,
                validL, seqs, nullptr, nullptr, nullptr, nullptr, nullptr);
        } else {
            ffn_kernel<1><<<dim3(1600), dim3(64), 0, stream>>>(
                attno, outWb + (size_t)i * 16384, outB + i * 128, Qn,
                fwd_g + i * 128, fwd_b + i * 128,
                c1b_w + (size_t)i * 16384, c1b + i * 128,
                c2b_w + (size_t)i * 16384, c2b + i * 128,
                validL, nullptr, last_g, last_b, G, negt, outF);
        }
    }
}